// Round 1
// baseline (195.967 us; speedup 1.0000x reference)
//
#include <hip/hip_runtime.h>
#include <math.h>

#define B_    8
#define HP    16
#define WPW   16
#define CIN   32
#define COUT  64
#define NSITE (B_*HP*WPW)           // 2048

// flat output offsets (floats), in reference return order
#define OFF_XOUT 0
#define OFF_AGR  (NSITE*COUT)              // 131072
#define OFF_POSE (OFF_AGR + NSITE*COUT)    // 262144
#define OFF_XP   (OFF_POSE + NSITE*COUT*2) // 524288

// ---------------------------------------------------------------------------
// Kernel A: per site -- pooled means, tpos, h = tg1 @ tpos (4x32 per site),
// plus xp max-pool and x_out = xp @ lin_w^T + lin_b.
// One block of 128 threads per site; thread t -> (p = t>>5, ci = t&31).
// ---------------------------------------------------------------------------
__global__ __launch_bounds__(128) void capsA(
    const float* __restrict__ x, const float* __restrict__ pose,
    const float* __restrict__ tg1, const float* __restrict__ lin_w,
    const float* __restrict__ lin_b, float* __restrict__ out,
    float* __restrict__ ws_h)
{
    const int s  = blockIdx.x;
    const int b  = s >> 8;
    const int hp = (s >> 4) & 15;
    const int wp = s & 15;
    const int t  = threadIdx.x;
    const int p  = t >> 5, ci = t & 31;
    const int dh = p >> 1, dw = p & 1;
    const int yy = 2*hp + dh, xx = 2*wp + dw;

    __shared__ float spx[128], spy[128], sxv[128];
    __shared__ float smx[32],  smy[32],  sxp[32];
    __shared__ float stp[4*64];   // tpos, layout [p][2*ci+comp]

    const int gidx = (((b*32 + yy)*32 + xx)*32 + ci);
    const float2 pv = ((const float2*)pose)[gidx];
    spx[t] = pv.x; spy[t] = pv.y;
    sxv[t] = x[gidx];
    __syncthreads();

    if (t < 32) {
        float mx = 0.f, my = 0.f, xm = -INFINITY;
        #pragma unroll
        for (int q = 0; q < 4; q++) {
            mx += spx[q*32 + t];
            my += spy[q*32 + t];
            xm  = fmaxf(xm, sxv[q*32 + t]);
        }
        const float n   = sqrtf(mx*mx + my*my);
        const float den = n + (n == 0.0f ? 1.0f : 0.0f);  // n + (1 - sign(n))
        smx[t] = mx / den;
        smy[t] = my / den;
        sxp[t] = xm;
        out[OFF_XP + s*32 + t] = xm;
    }
    __syncthreads();

    // tpos = rot(inverse(mean)) @ pool_grid; rot = [[mx,my],[-my,mx]]
    {
        const float hh = (float)dh - 0.5f;
        const float ww = (float)dw - 0.5f;
        const float mx = smx[ci], my = smy[ci];
        stp[p*64 + 2*ci    ] =  mx*hh + my*ww;
        stp[p*64 + 2*ci + 1] = -my*hh + mx*ww;
    }
    __syncthreads();

    // h[p][j] = sum_m tg1[j][m] * tpos[p][m], thread (p, j=ci)
    {
        const float* w = tg1 + ci*64;
        const float* v = stp + p*64;
        float acc = 0.f;
        #pragma unroll
        for (int k = 0; k < 64; k++) acc += w[k]*v[k];
        ws_h[s*128 + p*32 + ci] = acc;
    }

    // x_out[co] = lin_b[co] + sum_ci xp[ci]*lin_w[co][ci]
    if (t < 64) {
        float acc = lin_b[t];
        const float* w = lin_w + t*32;
        #pragma unroll
        for (int k = 0; k < 32; k++) acc += w[k]*sxp[k];
        out[OFF_XOUT + s*64 + t] = acc;
    }
}

// ---------------------------------------------------------------------------
// Kernel B: one wave per (site, co). Block = 4 waves = 4 sites, fixed co.
// Lane l owns vote elements e = l and e = l+64 -> same ci = l&31,
// p0 = l>>5 and p1 = p0+2 (one shared tg2 row per lane).
// ---------------------------------------------------------------------------
__global__ __launch_bounds__(256) void capsB(
    const float* __restrict__ a, const float* __restrict__ pose,
    const float* __restrict__ tg2, const float* __restrict__ ws_h,
    const float* __restrict__ alpha, const float* __restrict__ beta,
    float* __restrict__ out)
{
    const int co   = blockIdx.x;
    const int tid  = threadIdx.x;
    const int wave = tid >> 6, lane = tid & 63;
    const int s    = blockIdx.y*4 + wave;

    __shared__ float tg2s[32*36];   // 32 rows, padded stride 36 (16B-aligned, 2-way bank alias only)
    __shared__ float hs[4*128];     // h for the block's 4 sites

    for (int i = tid; i < 1024; i += 256)
        tg2s[(i >> 5)*36 + (i & 31)] = tg2[co*1024 + i];
    for (int i = tid; i < 512; i += 256)
        hs[i] = ws_h[blockIdx.y*512 + i];
    __syncthreads();

    const int ci = lane & 31, p0 = lane >> 5, p1 = p0 + 2;

    // theta = tg2_row(co*32+ci) . h[p]
    float th0 = 0.f, th1 = 0.f;
    {
        const float4* row = (const float4*)(tg2s + ci*36);
        const float4* h0  = (const float4*)(hs + wave*128 + p0*32);
        const float4* h1  = (const float4*)(hs + wave*128 + p1*32);
        #pragma unroll
        for (int k = 0; k < 8; k++) {
            const float4 r = row[k], u = h0[k], v = h1[k];
            th0 += r.x*u.x + r.y*u.y + r.z*u.z + r.w*u.w;
            th1 += r.x*v.x + r.y*v.y + r.z*v.z + r.w*v.w;
        }
    }
    float s0, c0, s1, c1;
    __sincosf(th0, &s0, &c0);
    __sincosf(th1, &s1, &c1);

    const int b  = s >> 8, hp = (s >> 4) & 15, wp = s & 15;
    const int y0 = 2*hp + (p0 >> 1), x0 = 2*wp + (p0 & 1);
    const int y1 = 2*hp + (p1 >> 1), x1 = 2*wp + (p1 & 1);
    const int i0 = (((b*32 + y0)*32 + x0)*32 + ci);
    const int i1 = (((b*32 + y1)*32 + x1)*32 + ci);
    const float2 pe0 = ((const float2*)pose)[i0];
    const float2 pe1 = ((const float2*)pose)[i1];
    const float a0 = a[i0], a1 = a[i1];

    // vote = pose rotated by theta
    const float v0x = pe0.x*c0 - pe0.y*s0, v0y = pe0.y*c0 + pe0.x*s0;
    const float v1x = pe1.x*c1 - pe1.y*s1, v1y = pe1.y*c1 + pe1.x*s1;

    float w0 = a0, w1 = a1;
    float pox = 0.f, poy = 0.f;

    #pragma unroll
    for (int it = 0; it < 4; it++) {
        float mx = v0x*w0 + v1x*w1;
        float my = v0y*w0 + v1y*w1;
        #pragma unroll
        for (int m = 1; m < 64; m <<= 1) {
            mx += __shfl_xor(mx, m, 64);
            my += __shfl_xor(my, m, 64);
        }
        const float n = sqrtf(mx*mx + my*my);
        pox = mx / (n + (mx == 0.0f ? 1.0f : 0.0f));  // n + (1 - sign|mu_x|)
        poy = my / (n + (my == 0.0f ? 1.0f : 0.0f));
        if (it < 3) {
            const float d0 = 0.5f*(1.0f - (pox*v0x + poy*v0y));
            const float d1 = 0.5f*(1.0f - (pox*v1x + poy*v1y));
            w0 = (1.0f - d0)*a0;
            w1 = (1.0f - d1)*a1;
        }
    }

    // nd with final pose_o and last weight
    const float d0 = 0.5f*(1.0f - (pox*v0x + poy*v0y));
    const float d1 = 0.5f*(1.0f - (pox*v1x + poy*v1y));
    float nd = (1.0f - d0)*w0 + (1.0f - d1)*w1;
    float wc = (w0 != 0.0f ? 1.0f : 0.0f) + (w1 != 0.0f ? 1.0f : 0.0f);
    #pragma unroll
    for (int m = 1; m < 64; m <<= 1) {
        nd += __shfl_xor(nd, m, 64);
        wc += __shfl_xor(wc, m, 64);
    }

    if (lane == 0) {
        const float msk = (wc != 0.0f) ? 1.0f : 0.0f;
        const float res = nd / (wc + (1.0f - msk)) * msk;
        const float z   = alpha[0]*res + (beta[0] - 1.0f);
        const float agr = msk / (1.0f + __expf(-z));
        out[OFF_AGR  + s*64  + co]       = agr;
        out[OFF_POSE + s*128 + co*2]     = pox;
        out[OFF_POSE + s*128 + co*2 + 1] = poy;
    }
}

extern "C" void kernel_launch(void* const* d_in, const int* in_sizes, int n_in,
                              void* d_out, int out_size, void* d_ws, size_t ws_size,
                              hipStream_t stream) {
    const float* x     = (const float*)d_in[0];
    const float* a     = (const float*)d_in[1];
    const float* pose  = (const float*)d_in[2];
    const float* alpha = (const float*)d_in[3];
    const float* beta  = (const float*)d_in[4];
    const float* lin_w = (const float*)d_in[5];
    const float* lin_b = (const float*)d_in[6];
    const float* tg1   = (const float*)d_in[7];
    const float* tg2   = (const float*)d_in[8];
    float* out  = (float*)d_out;
    float* ws_h = (float*)d_ws;   // 2048 sites * 128 floats = 1 MB

    capsA<<<NSITE, 128, 0, stream>>>(x, pose, tg1, lin_w, lin_b, out, ws_h);
    capsB<<<dim3(COUT, NSITE/4), 256, 0, stream>>>(a, pose, tg2, ws_h, alpha, beta, out);
}

// Round 2
// 147.449 us; speedup vs baseline: 1.3291x; 1.3291x over previous
//
#include <hip/hip_runtime.h>
#include <math.h>

#define NSITE 2048

// flat output offsets (floats), reference return order
#define OFF_XOUT 0
#define OFF_AGR  (NSITE*64)                // 131072
#define OFF_POSE (OFF_AGR + NSITE*64)      // 262144
#define OFF_XP   (OFF_POSE + NSITE*128)    // 524288

// ws layout: ws_h [2048][128] floats (1 MB), then ws_meta [2048] float2 (16 KB)
#define WS_META_OFF (NSITE*128)

// guarded normalize matching ref semantics: out_c = (mu_c==0) ? 0 : mu_c/||mu||
__device__ __forceinline__ void norm2_guard(float x, float y, float* ox, float* oy) {
    const float n2  = x*x + y*y;
    const float inv = (n2 > 0.f) ? rsqrtf(n2) : 0.f;
    *ox = x*inv; *oy = y*inv;
}

// ---------------------------------------------------------------------------
// Kernel A: per site -- pooled means, tpos, h = tg1 @ tpos, xp max-pool,
// x_out = xp @ lin_w^T + lin_b, plus Sa = sum(a) and cnt = #(a!=0) per site.
// One block of 128 threads per site; thread t -> (p = t>>5, ci = t&31).
// ---------------------------------------------------------------------------
__global__ __launch_bounds__(128) void capsA(
    const float* __restrict__ x, const float* __restrict__ a,
    const float* __restrict__ pose,
    const float* __restrict__ tg1, const float* __restrict__ lin_w,
    const float* __restrict__ lin_b, float* __restrict__ out,
    float* __restrict__ ws)
{
    const int s  = blockIdx.x;
    const int b  = s >> 8;
    const int hp = (s >> 4) & 15;
    const int wp = s & 15;
    const int t  = threadIdx.x;
    const int p  = t >> 5, ci = t & 31;
    const int dh = p >> 1, dw = p & 1;
    const int yy = 2*hp + dh, xx = 2*wp + dw;

    __shared__ float spx[128], spy[128], sxv[128], sav[128];
    __shared__ float smx[32],  smy[32],  sxp[32];
    __shared__ float stp[4*64];   // tpos, layout [p][2*ci+comp]

    const int gidx = (((b*32 + yy)*32 + xx)*32 + ci);
    const float2 pv = ((const float2*)pose)[gidx];
    spx[t] = pv.x; spy[t] = pv.y;
    sxv[t] = x[gidx];
    sav[t] = a[gidx];
    __syncthreads();

    if (t < 32) {
        float mx = 0.f, my = 0.f, xm = -INFINITY, sa = 0.f, cnt = 0.f;
        #pragma unroll
        for (int q = 0; q < 4; q++) {
            mx += spx[q*32 + t];
            my += spy[q*32 + t];
            xm  = fmaxf(xm, sxv[q*32 + t]);
            const float av = sav[q*32 + t];
            sa += av;
            cnt += (av != 0.f) ? 1.f : 0.f;
        }
        const float n   = sqrtf(mx*mx + my*my);
        const float den = n + (n == 0.0f ? 1.0f : 0.0f);  // n + (1 - sign(n))
        smx[t] = mx / den;
        smy[t] = my / den;
        sxp[t] = xm;
        out[OFF_XP + s*32 + t] = xm;
        // reduce Sa / cnt across the 32 lanes (all within wave 0)
        #pragma unroll
        for (int m = 1; m <= 16; m <<= 1) {
            sa  += __shfl_xor(sa,  m, 64);
            cnt += __shfl_xor(cnt, m, 64);
        }
        if (t == 0) ((float2*)(ws + WS_META_OFF))[s] = make_float2(sa, cnt);
    }
    __syncthreads();

    // tpos = rot(inverse(mean)) @ pool_grid; rot = [[mx,my],[-my,mx]]
    {
        const float hh = (float)dh - 0.5f;
        const float ww = (float)dw - 0.5f;
        const float mx = smx[ci], my = smy[ci];
        stp[p*64 + 2*ci    ] =  mx*hh + my*ww;
        stp[p*64 + 2*ci + 1] = -my*hh + mx*ww;
    }
    __syncthreads();

    // h[p][j] = sum_m tg1[j][m] * tpos[p][m], thread (p, j=ci)
    {
        const float* w = tg1 + ci*64;
        const float* v = stp + p*64;
        float acc = 0.f;
        #pragma unroll
        for (int k = 0; k < 64; k++) acc += w[k]*v[k];
        ws[s*128 + p*32 + ci] = acc;
    }

    // x_out[co] = lin_b[co] + sum_ci xp[ci]*lin_w[co][ci]
    if (t < 64) {
        float acc = lin_b[t];
        const float* w = lin_w + t*32;
        #pragma unroll
        for (int k = 0; k < 32; k++) acc += w[k]*sxp[k];
        out[OFF_XOUT + s*64 + t] = acc;
    }
}

// ---------------------------------------------------------------------------
// Kernel B: moment-based routing. Block = 4 waves; wave w owns 2 output caps
// (co = g*8 + 2w + lane>>5), lane's ci = lane&31; loops over 8 sites.
// Each lane caches its tg2 row in 32 VGPRs; h is read wave-uniform from ws.
// Routing fixed point runs on closed-form moments -- no per-iter reductions.
// No LDS allocation; only 25 swizzles (one 5-moment butterfly) per site.
// ---------------------------------------------------------------------------
__global__ __launch_bounds__(256) void capsB(
    const float* __restrict__ a, const float* __restrict__ pose,
    const float* __restrict__ tg2, const float* __restrict__ ws,
    const float* __restrict__ alpha, const float* __restrict__ beta,
    float* __restrict__ out)
{
    const int g    = blockIdx.x;            // co-group 0..7
    const int sb   = blockIdx.y;            // site block 0..255
    const int tid  = threadIdx.x;
    const int wave = tid >> 6, lane = tid & 63;
    const int co   = g*8 + wave*2 + (lane >> 5);
    const int ci   = lane & 31;

    // cache tg2 row (32 floats) in registers -- loaded once, reused for 8 sites
    float4 r[8];
    {
        const float4* rp = (const float4*)(tg2 + (co*32 + ci)*32);
        #pragma unroll
        for (int k = 0; k < 8; ++k) r[k] = rp[k];
    }
    const float alp = alpha[0];
    const float bet = beta[0] - 1.0f;
    const float2* ws_meta = (const float2*)(ws + WS_META_OFF);

    const int s0 = sb*8;
    for (int s = s0; s < s0 + 8; ++s) {
        // theta[p] = tg2_row(co*32+ci) . h[s][p]   (h loads are wave-uniform)
        const float4* h4 = (const float4*)(ws + s*128);
        float th0 = 0.f, th1 = 0.f, th2 = 0.f, th3 = 0.f;
        #pragma unroll
        for (int k = 0; k < 8; ++k) {
            const float4 rk = r[k];
            const float4 ha = h4[k];
            const float4 hb = h4[8  + k];
            const float4 hc = h4[16 + k];
            const float4 hd = h4[24 + k];
            th0 += rk.x*ha.x + rk.y*ha.y + rk.z*ha.z + rk.w*ha.w;
            th1 += rk.x*hb.x + rk.y*hb.y + rk.z*hb.z + rk.w*hb.w;
            th2 += rk.x*hc.x + rk.y*hc.y + rk.z*hc.z + rk.w*hc.w;
            th3 += rk.x*hd.x + rk.y*hd.y + rk.z*hd.z + rk.w*hd.w;
        }
        const float th[4] = {th0, th1, th2, th3};

        const int b   = s >> 8, hpi = (s >> 4) & 15, wpi = s & 15;
        const int base = ((b*32 + 2*hpi)*32 + 2*wpi)*32 + ci;

        float Sx = 0.f, Sy = 0.f, Sxx = 0.f, Sxy = 0.f, Syy = 0.f;
        #pragma unroll
        for (int p = 0; p < 4; ++p) {
            const int idx = base + (p >> 1)*1024 + (p & 1)*32;
            const float2 pe = ((const float2*)pose)[idx];
            const float  av = a[idx];
            float sn, cs;
            __sincosf(th[p], &sn, &cs);
            const float vx = pe.x*cs - pe.y*sn;   // vote = rot(theta) @ pose
            const float vy = pe.y*cs + pe.x*sn;
            const float ax = av*vx, ay = av*vy;
            Sx += ax; Sy += ay;
            Sxx += ax*vx; Sxy += ax*vy; Syy += ay*vy;
        }
        // one butterfly over the 32 lanes of this co-half (masks 1..16)
        #pragma unroll
        for (int m = 1; m <= 16; m <<= 1) {
            Sx  += __shfl_xor(Sx,  m, 64);
            Sy  += __shfl_xor(Sy,  m, 64);
            Sxx += __shfl_xor(Sxx, m, 64);
            Sxy += __shfl_xor(Sxy, m, 64);
            Syy += __shfl_xor(Syy, m, 64);
        }

        // fixed point on moments (all lanes redundantly; stores from lane 0/32)
        // mu(p) = (Sx + px*Sxx + py*Sxy, Sy + px*Sxy + py*Syy)  [0.5 dropped:
        // scale-invariant under the guarded normalize]
        float px, py;
        norm2_guard(Sx, Sy, &px, &py);            // p0 (weight = a)
        float qx = px, qy = py;
        #pragma unroll
        for (int it = 0; it < 3; ++it) {
            qx = px; qy = py;                     // ends as p2
            const float mx = Sx + px*Sxx + py*Sxy;
            const float my = Sy + px*Sxy + py*Syy;
            norm2_guard(mx, my, &px, &py);        // ends as p3
        }
        const float2 meta = ws_meta[s];           // (Sa, count(a!=0))
        const float nd_sum = 0.25f*(meta.x + (px + qx)*Sx + (py + qy)*Sy
                           + px*qx*Sxx + (px*qy + py*qx)*Sxy + py*qy*Syy);
        const float wsum = meta.y;
        const float msk  = (wsum != 0.f) ? 1.f : 0.f;
        const float nd   = nd_sum / (wsum + (1.f - msk)) * msk;
        const float z    = alp*nd + bet;
        const float agr  = msk / (1.f + __expf(-z));

        if ((lane & 31) == 0) {
            out[OFF_AGR  + s*64  + co]       = agr;
            out[OFF_POSE + s*128 + co*2]     = px;
            out[OFF_POSE + s*128 + co*2 + 1] = py;
        }
    }
}

extern "C" void kernel_launch(void* const* d_in, const int* in_sizes, int n_in,
                              void* d_out, int out_size, void* d_ws, size_t ws_size,
                              hipStream_t stream) {
    const float* x     = (const float*)d_in[0];
    const float* a     = (const float*)d_in[1];
    const float* pose  = (const float*)d_in[2];
    const float* alpha = (const float*)d_in[3];
    const float* beta  = (const float*)d_in[4];
    const float* lin_w = (const float*)d_in[5];
    const float* lin_b = (const float*)d_in[6];
    const float* tg1   = (const float*)d_in[7];
    const float* tg2   = (const float*)d_in[8];
    float* out = (float*)d_out;
    float* ws  = (float*)d_ws;   // 1 MB h + 16 KB meta

    capsA<<<NSITE, 128, 0, stream>>>(x, a, pose, tg1, lin_w, lin_b, out, ws);
    capsB<<<dim3(8, NSITE/8), 256, 0, stream>>>(a, pose, tg2, ws, alpha, beta, out);
}

// Round 7
// 144.367 us; speedup vs baseline: 1.3574x; 1.0213x over previous
//
#include <hip/hip_runtime.h>
#include <math.h>

#define NSITE 2048

// flat output offsets (floats), reference return order
#define OFF_XOUT 0
#define OFF_AGR  (NSITE*64)                // 131072
#define OFF_POSE (OFF_AGR + NSITE*64)      // 262144
#define OFF_XP   (OFF_POSE + NSITE*128)    // 524288

// ws layout: ws_h [2048][128] floats (1 MB), then ws_meta [2048] float2 (16 KB)
#define WS_META_OFF (NSITE*128)

// guarded normalize matching ref semantics: out_c = (mu_c==0) ? 0 : mu_c/||mu||
__device__ __forceinline__ void norm2_guard(float x, float y, float* ox, float* oy) {
    const float n2  = x*x + y*y;
    const float inv = (n2 > 0.f) ? rsqrtf(n2) : 0.f;
    *ox = x*inv; *oy = y*inv;
}

// ---------------------------------------------------------------------------
// Kernel A: one wave per site; 4 sites per 256-thread block; 512 blocks.
// Lane l: ci = l&31, p0 = l>>5; owns pool positions p0 (dh=0,dw=p0) and
// p0+2 (dh=1,dw=p0). Pool reductions via __shfl_xor(.,32); reference
// p-order preserved for the pose mean (feeds the sensitive fixed point).
// Outputs x_out/xp verified in R6 (asserted before the failing output).
// ---------------------------------------------------------------------------
__global__ __launch_bounds__(256) void capsA(
    const float* __restrict__ x, const float* __restrict__ a,
    const float* __restrict__ pose,
    const float* __restrict__ tg1, const float* __restrict__ lin_w,
    const float* __restrict__ lin_b, float* __restrict__ out,
    float* __restrict__ ws)
{
    const int wave = threadIdx.x >> 6, lane = threadIdx.x & 63;
    const int s  = blockIdx.x*4 + wave;
    const int b  = s >> 8, hp = (s >> 4) & 15, wp = s & 15;
    const int ci = lane & 31, p0 = lane >> 5;           // p0 in {0,1}

    __shared__ float stp[4][4][64];   // tpos per site: [wave][p][2ci+c]
    __shared__ float xps[4][32];      // pooled x-max per site

    const int base = ((b*32 + 2*hp)*32 + 2*wp)*32 + ci;
    const int i0 = base + p0*32;            // p = p0   (dh=0, dw=p0)
    const int i1 = base + 1024 + p0*32;     // p = p0+2 (dh=1, dw=p0)
    const float2 pe0 = ((const float2*)pose)[i0];
    const float2 pe1 = ((const float2*)pose)[i1];
    const float  x0  = x[i0], x1 = x[i1];
    const float  a0  = a[i0], a1 = a[i1];

    // pose pooling sum in exact reference order ((p0+p1)+p2)+p3
    const float o0x = __shfl_xor(pe0.x, 32, 64);
    const float o0y = __shfl_xor(pe0.y, 32, 64);
    const float o1x = __shfl_xor(pe1.x, 32, 64);
    const float o1y = __shfl_xor(pe1.y, 32, 64);
    const bool first = (p0 == 0);
    const float A0x = first ? pe0.x : o0x,  A1x = first ? o0x : pe0.x;
    const float A2x = first ? pe1.x : o1x,  A3x = first ? o1x : pe1.x;
    const float A0y = first ? pe0.y : o0y,  A1y = first ? o0y : pe0.y;
    const float A2y = first ? pe1.y : o1y,  A3y = first ? o1y : pe1.y;
    float mx = ((A0x + A1x) + A2x) + A3x;
    float my = ((A0y + A1y) + A2y) + A3y;

    // x max-pool, Sa, count(a != 0)
    float xm = fmaxf(x0, x1);
    xm = fmaxf(xm, __shfl_xor(xm, 32, 64));
    float sa  = a0 + a1;
    float cnt = (a0 != 0.f ? 1.f : 0.f) + (a1 != 0.f ? 1.f : 0.f);
    sa  += __shfl_xor(sa,  32, 64);
    cnt += __shfl_xor(cnt, 32, 64);
    // site totals over ci
    #pragma unroll
    for (int m = 1; m <= 16; m <<= 1) {
        sa  += __shfl_xor(sa,  m, 64);
        cnt += __shfl_xor(cnt, m, 64);
    }
    if (lane == 0) ((float2*)(ws + WS_META_OFF))[s] = make_float2(sa, cnt);
    if (p0 == 0) {
        out[OFF_XP + s*32 + ci] = xm;
        xps[wave][ci] = xm;
    }

    // guarded mean
    {
        const float n   = sqrtf(mx*mx + my*my);
        const float den = n + (n == 0.f ? 1.f : 0.f);
        mx /= den; my /= den;
    }

    // tpos = [[mx,my],[-my,mx]] @ (hh,ww); hh = dh-0.5, ww = p0-0.5
    {
        const float ww_ = (float)p0 - 0.5f;
        const float t0x = -0.5f*mx + my*ww_;    // p0   (hh=-0.5)
        const float t0y =  0.5f*my + mx*ww_;
        const float t1x =  0.5f*mx + my*ww_;    // p0+2 (hh=+0.5)
        const float t1y = -0.5f*my + mx*ww_;
        ((float2*)stp[wave][p0    ])[ci] = make_float2(t0x, t0y);
        ((float2*)stp[wave][p0 + 2])[ci] = make_float2(t1x, t1y);
    }
    __syncthreads();

    // h[p][j] = sum_m tg1[j][m]*tpos[p][m]; lane does (p0, j=ci), (p0+2, j=ci)
    {
        const float4* w4 = (const float4*)(tg1 + ci*64);
        const float4* r0 = (const float4*)stp[wave][p0];
        const float4* r1 = (const float4*)stp[wave][p0 + 2];
        float h0 = 0.f, h1 = 0.f;
        #pragma unroll
        for (int k = 0; k < 16; ++k) {
            const float4 wv = w4[k], u = r0[k], v = r1[k];
            h0 += wv.x*u.x + wv.y*u.y + wv.z*u.z + wv.w*u.w;
            h1 += wv.x*v.x + wv.y*v.y + wv.z*v.z + wv.w*v.w;
        }
        ws[s*128 + p0*32 + ci]       = h0;
        ws[s*128 + (p0 + 2)*32 + ci] = h1;
    }

    // x_out[co=lane] = lin_b + sum_ci xp[ci]*lin_w[co][ci]
    {
        float acc = lin_b[lane];
        const float4* lw = (const float4*)(lin_w + lane*32);
        const float4* xv = (const float4*)xps[wave];
        #pragma unroll
        for (int k = 0; k < 8; ++k) {
            const float4 wv = lw[k], u = xv[k];
            acc += wv.x*u.x + wv.y*u.y + wv.z*u.z + wv.w*u.w;
        }
        out[OFF_XOUT + s*64 + lane] = acc;
    }
}

// ---------------------------------------------------------------------------
// Kernel B: moment-based routing, VALU fp32 theta — VERBATIM the R2 kernel
// that passed (absmax 0.0039). The routing fixed point is bistable at one
// (site,co) with a ~1e-7 theta-perturbation margin (R4/R6 evidence: 2-way
// and 3-way split MFMA theta both land on the wrong attractor with
// bit-identical absmax 0.164). DO NOT change any arithmetic/expression
// order in this kernel.
// ---------------------------------------------------------------------------
__global__ __launch_bounds__(256) void capsB(
    const float* __restrict__ a, const float* __restrict__ pose,
    const float* __restrict__ tg2, const float* __restrict__ ws,
    const float* __restrict__ alpha, const float* __restrict__ beta,
    float* __restrict__ out)
{
    const int g    = blockIdx.x;            // co-group 0..7
    const int sb   = blockIdx.y;            // site block 0..255
    const int tid  = threadIdx.x;
    const int wave = tid >> 6, lane = tid & 63;
    const int co   = g*8 + wave*2 + (lane >> 5);
    const int ci   = lane & 31;

    // cache tg2 row (32 floats) in registers -- loaded once, reused for 8 sites
    float4 r[8];
    {
        const float4* rp = (const float4*)(tg2 + (co*32 + ci)*32);
        #pragma unroll
        for (int k = 0; k < 8; ++k) r[k] = rp[k];
    }
    const float alp = alpha[0];
    const float bet = beta[0] - 1.0f;
    const float2* ws_meta = (const float2*)(ws + WS_META_OFF);

    const int s0 = sb*8;
    for (int s = s0; s < s0 + 8; ++s) {
        // theta[p] = tg2_row(co*32+ci) . h[s][p]   (h loads are wave-uniform)
        const float4* h4 = (const float4*)(ws + s*128);
        float th0 = 0.f, th1 = 0.f, th2 = 0.f, th3 = 0.f;
        #pragma unroll
        for (int k = 0; k < 8; ++k) {
            const float4 rk = r[k];
            const float4 ha = h4[k];
            const float4 hb = h4[8  + k];
            const float4 hc = h4[16 + k];
            const float4 hd = h4[24 + k];
            th0 += rk.x*ha.x + rk.y*ha.y + rk.z*ha.z + rk.w*ha.w;
            th1 += rk.x*hb.x + rk.y*hb.y + rk.z*hb.z + rk.w*hb.w;
            th2 += rk.x*hc.x + rk.y*hc.y + rk.z*hc.z + rk.w*hc.w;
            th3 += rk.x*hd.x + rk.y*hd.y + rk.z*hd.z + rk.w*hd.w;
        }
        const float th[4] = {th0, th1, th2, th3};

        const int b   = s >> 8, hpi = (s >> 4) & 15, wpi = s & 15;
        const int base = ((b*32 + 2*hpi)*32 + 2*wpi)*32 + ci;

        float Sx = 0.f, Sy = 0.f, Sxx = 0.f, Sxy = 0.f, Syy = 0.f;
        #pragma unroll
        for (int p = 0; p < 4; ++p) {
            const int idx = base + (p >> 1)*1024 + (p & 1)*32;
            const float2 pe = ((const float2*)pose)[idx];
            const float  av = a[idx];
            float sn, cs;
            __sincosf(th[p], &sn, &cs);
            const float vx = pe.x*cs - pe.y*sn;   // vote = rot(theta) @ pose
            const float vy = pe.y*cs + pe.x*sn;
            const float ax = av*vx, ay = av*vy;
            Sx += ax; Sy += ay;
            Sxx += ax*vx; Sxy += ax*vy; Syy += ay*vy;
        }
        // one butterfly over the 32 lanes of this co-half (masks 1..16)
        #pragma unroll
        for (int m = 1; m <= 16; m <<= 1) {
            Sx  += __shfl_xor(Sx,  m, 64);
            Sy  += __shfl_xor(Sy,  m, 64);
            Sxx += __shfl_xor(Sxx, m, 64);
            Sxy += __shfl_xor(Sxy, m, 64);
            Syy += __shfl_xor(Syy, m, 64);
        }

        // fixed point on moments (all lanes redundantly; stores from lane 0/32)
        // mu(p) = (Sx + px*Sxx + py*Sxy, Sy + px*Sxy + py*Syy)  [0.5 dropped:
        // scale-invariant under the guarded normalize]
        float px, py;
        norm2_guard(Sx, Sy, &px, &py);            // p0 (weight = a)
        float qx = px, qy = py;
        #pragma unroll
        for (int it = 0; it < 3; ++it) {
            qx = px; qy = py;                     // ends as p2
            const float mx = Sx + px*Sxx + py*Sxy;
            const float my = Sy + px*Sxy + py*Syy;
            norm2_guard(mx, my, &px, &py);        // ends as p3
        }
        const float2 meta = ws_meta[s];           // (Sa, count(a!=0))
        const float nd_sum = 0.25f*(meta.x + (px + qx)*Sx + (py + qy)*Sy
                           + px*qx*Sxx + (px*qy + py*qx)*Sxy + py*qy*Syy);
        const float wsum = meta.y;
        const float msk  = (wsum != 0.f) ? 1.f : 0.f;
        const float nd   = nd_sum / (wsum + (1.f - msk)) * msk;
        const float z    = alp*nd + bet;
        const float agr  = msk / (1.f + __expf(-z));

        if ((lane & 31) == 0) {
            out[OFF_AGR  + s*64  + co]       = agr;
            out[OFF_POSE + s*128 + co*2]     = px;
            out[OFF_POSE + s*128 + co*2 + 1] = py;
        }
    }
}

extern "C" void kernel_launch(void* const* d_in, const int* in_sizes, int n_in,
                              void* d_out, int out_size, void* d_ws, size_t ws_size,
                              hipStream_t stream) {
    const float* x     = (const float*)d_in[0];
    const float* a     = (const float*)d_in[1];
    const float* pose  = (const float*)d_in[2];
    const float* alpha = (const float*)d_in[3];
    const float* beta  = (const float*)d_in[4];
    const float* lin_w = (const float*)d_in[5];
    const float* lin_b = (const float*)d_in[6];
    const float* tg1   = (const float*)d_in[7];
    const float* tg2   = (const float*)d_in[8];
    float* out = (float*)d_out;
    float* ws  = (float*)d_ws;   // 1 MB h + 16 KB meta

    capsA<<<NSITE/4, 256, 0, stream>>>(x, a, pose, tg1, lin_w, lin_b, out, ws);
    capsB<<<dim3(8, NSITE/8), 256, 0, stream>>>(a, pose, tg2, ws, alpha, beta, out);
}